// Round 1
// baseline (84.663 us; speedup 1.0000x reference)
//
#include <hip/hip_runtime.h>

#define NUM_CENTERS 16

typedef float nfloat4 __attribute__((ext_vector_type(4)));

// Tree-structured argmin over |v - c[i]|.
// Combine keeps the LEFT (lower original index) operand on ties (strict <
// for the right operand), so the overall winner is the first index attaining
// the min — exactly jnp.argmin semantics. 4-deep dependency chain instead of
// the 15-deep serial select chain.
__device__ __forceinline__ float nearest_center(float v, const float* __restrict__ c) {
    float d[NUM_CENTERS];
    float val[NUM_CENTERS];
#pragma unroll
    for (int i = 0; i < NUM_CENTERS; ++i) {
        d[i]   = fabsf(v - c[i]);
        val[i] = c[i];
    }
#pragma unroll
    for (int stride = 1; stride < NUM_CENTERS; stride <<= 1) {
#pragma unroll
        for (int i = 0; i < NUM_CENTERS; i += 2 * stride) {
            bool r = d[i + stride] < d[i];   // right wins only on strict less
            d[i]   = r ? d[i + stride]   : d[i];
            val[i] = r ? val[i + stride] : val[i];
        }
    }
    return val[0];
}

__device__ __forceinline__ nfloat4 map4(nfloat4 v, const float* __restrict__ c) {
    nfloat4 r;
    r.x = nearest_center(v.x, c);
    r.y = nearest_center(v.y, c);
    r.z = nearest_center(v.z, c);
    r.w = nearest_center(v.w, c);
    return r;
}

__global__ __launch_bounds__(256) void nearest_center_kernel(
    const float* __restrict__ x,
    const float* __restrict__ centers,
    float* __restrict__ out,
    int n4)  // number of float4 groups
{
    // Wave-uniform center loads -> scalar loads, broadcast.
    float c[NUM_CENTERS];
#pragma unroll
    for (int i = 0; i < NUM_CENTERS; ++i) c[i] = centers[i];

    const nfloat4* __restrict__ xv = reinterpret_cast<const nfloat4*>(x);
    nfloat4* __restrict__ ov       = reinterpret_cast<nfloat4*>(out);

    int t        = blockIdx.x * blockDim.x + threadIdx.x;
    int nthreads = gridDim.x * blockDim.x;

    int i0 = t;
    int i1 = t + nthreads;   // second coalesced stream

    bool p0 = i0 < n4;
    bool p1 = i1 < n4;

    // Issue both loads before any compute so HBM latency overlaps the tree.
    nfloat4 v0, v1;
    if (p0) v0 = xv[i0];
    if (p1) v1 = xv[i1];

    if (p0) {
        nfloat4 r0 = map4(v0, c);
        __builtin_nontemporal_store(r0, ov + i0);  // write-once output
    }
    if (p1) {
        nfloat4 r1 = map4(v1, c);
        __builtin_nontemporal_store(r1, ov + i1);
    }
}

extern "C" void kernel_launch(void* const* d_in, const int* in_sizes, int n_in,
                              void* d_out, int out_size, void* d_ws, size_t ws_size,
                              hipStream_t stream) {
    const float* x       = (const float*)d_in[0];   // (8,64,64,64) fp32, 2,097,152 elems
    const float* centers = (const float*)d_in[1];   // (16,) fp32
    float* out           = (float*)d_out;

    int n  = in_sizes[0];        // 2,097,152 (multiple of 4)
    int n4 = n / 4;              // 524,288 float4 groups

    const int block = 256;
    const int f4_per_thread = 2;
    int threads_needed = (n4 + f4_per_thread - 1) / f4_per_thread;   // 262,144
    int grid = (threads_needed + block - 1) / block;                 // 1024 workgroups
    nearest_center_kernel<<<grid, block, 0, stream>>>(x, centers, out, n4);
}

// Round 2
// 62.549 us; speedup vs baseline: 1.3535x; 1.3535x over previous
//
#include <hip/hip_runtime.h>

#define NUM_CENTERS 16

__device__ __forceinline__ float nearest_center(float v, const float* __restrict__ c) {
    // argmin over |v - c[i]|, first index wins ties (strict <), matching jnp.argmin
    float best_val = c[0];
    float best_d   = fabsf(v - c[0]);
#pragma unroll
    for (int i = 1; i < NUM_CENTERS; ++i) {
        float d = fabsf(v - c[i]);
        if (d < best_d) { best_d = d; best_val = c[i]; }
    }
    return best_val;
}

__global__ __launch_bounds__(256) void nearest_center_kernel(
    const float* __restrict__ x,
    const float* __restrict__ centers,
    float* __restrict__ out,
    int n4)  // number of float4 groups
{
    // Load centers into registers: wave-uniform addresses -> broadcast, L1/L2 cached.
    float c[NUM_CENTERS];
#pragma unroll
    for (int i = 0; i < NUM_CENTERS; ++i) c[i] = centers[i];

    int idx = blockIdx.x * blockDim.x + threadIdx.x;
    if (idx < n4) {
        float4 v = reinterpret_cast<const float4*>(x)[idx];
        float4 r;
        r.x = nearest_center(v.x, c);
        r.y = nearest_center(v.y, c);
        r.z = nearest_center(v.z, c);
        r.w = nearest_center(v.w, c);
        reinterpret_cast<float4*>(out)[idx] = r;
    }
}

extern "C" void kernel_launch(void* const* d_in, const int* in_sizes, int n_in,
                              void* d_out, int out_size, void* d_ws, size_t ws_size,
                              hipStream_t stream) {
    const float* x       = (const float*)d_in[0];   // (8,64,64,64) fp32, 2,097,152 elems
    const float* centers = (const float*)d_in[1];   // (16,) fp32
    float* out           = (float*)d_out;

    int n  = in_sizes[0];        // 2,097,152 (multiple of 4)
    int n4 = n / 4;              // 524,288 float4 groups

    const int block = 256;
    int grid = (n4 + block - 1) / block;  // 2048 blocks
    nearest_center_kernel<<<grid, block, 0, stream>>>(x, centers, out, n4);
}